// Round 2
// baseline (930.019 us; speedup 1.0000x reference)
//
#include <hip/hip_runtime.h>

#define BB 8
#define HH 512
#define WW 1024
#define TILE 32
#define HALO 2
#define LW (TILE + 2*HALO)   // 36
#define NIT ((LW*LW + 255) / 256)   // 6 halo iterations per thread

__device__ __forceinline__ float sigm(float v) { return 1.0f / (1.0f + __expf(-v)); }

// load (row[x0], row[x0+1]) with x clamped to [0, W-1]
__device__ __forceinline__ float2 ld2c(const float* __restrict__ row, int x0) {
    if ((unsigned)x0 < (unsigned)(WW - 1)) {
        return *reinterpret_cast<const float2*>(row + x0);
    }
    float v = row[x0 < 0 ? 0 : WW - 1];
    return make_float2(v, v);
}

// bilinear sample of C planar channels at (gx,gy), border-clamped, float2 taps
template<int C>
__device__ __forceinline__ void bilinN(const float* __restrict__ base,  // channel-0 plane of batch b
                                       float gx, float gy, float out[C]) {
    const size_t plane = (size_t)HH * WW;
    float x0f = floorf(gx), y0f = floorf(gy);
    float ax = gx - x0f, ay = gy - y0f;
    int x0 = (int)x0f, y0 = (int)y0f;
    int y0i = min(max(y0, 0), HH - 1);
    int y1i = min(max(y0 + 1, 0), HH - 1);
    float w00 = (1.f - ay) * (1.f - ax), w01 = (1.f - ay) * ax;
    float w10 = ay * (1.f - ax), w11 = ay * ax;
#pragma unroll
    for (int c = 0; c < C; ++c) {
        const float* pl = base + c * plane;
        float2 r0 = ld2c(pl + (size_t)y0i * WW, x0);
        float2 r1 = ld2c(pl + (size_t)y1i * WW, x0);
        out[c] = w00 * r0.x + w01 * r0.y + w10 * r1.x + w11 * r1.y;
    }
}

// Both directions in one dispatch: blockIdx.z = dir*BB + b
__global__ __launch_bounds__(256, 4)
void dir_kernel(const float* __restrict__ flowf, const float* __restrict__ flowb_,
                const float* __restrict__ img1, const float* __restrict__ img2,
                const float* __restrict__ target, float* __restrict__ acc) {
    __shared__ float lds_w[3][LW][LW];  // warped imgb (0 outside image = zero-pad)
    __shared__ float lds_a[3][LW][LW];  // imga        (0 outside image)
    __shared__ float red[8];

    const int z = blockIdx.z;
    const int dir = z >> 3;
    const int b = z & 7;
    const float* flowa = dir ? flowb_ : flowf;
    const float* flowb = dir ? flowf : flowb_;
    const float* imga  = dir ? img2 : img1;
    const float* imgb  = dir ? img1 : img2;

    const int tx0 = blockIdx.x * TILE;
    const int ty0 = blockIdx.y * TILE;
    const int tid = threadIdx.x;
    const size_t plane = (size_t)HH * WW;
    const size_t fbase = (size_t)(b * 2) * plane;   // flow batch base
    const size_t ibase = (size_t)(b * 3) * plane;   // image batch base

    // ---- Phase A: batched flow loads for all halo slots ----
    float fxs[NIT], fys[NIT];
#pragma unroll
    for (int it = 0; it < NIT; ++it) {
        int p = tid + it * 256;
        int hy = p / LW, hx = p - hy * LW;
        int gy = ty0 + hy - HALO, gx = tx0 + hx - HALO;
        float fx = 0.f, fy = 0.f;
        if (p < LW * LW && (unsigned)gx < WW && (unsigned)gy < HH) {
            size_t fi = fbase + (size_t)gy * WW + gx;
            fx = flowa[fi];
            fy = flowa[fi + plane];
        }
        fxs[it] = fx; fys[it] = fy;
    }

    // ---- Phase B: warp imgb, stage imga ----
#pragma unroll
    for (int it = 0; it < NIT; ++it) {
        int p = tid + it * 256;
        if (p < LW * LW) {
            int hy = p / LW, hx = p - hy * LW;
            int gy = ty0 + hy - HALO, gx = tx0 + hx - HALO;
            float w[3] = {0.f, 0.f, 0.f};
            float a0 = 0.f, a1 = 0.f, a2 = 0.f;
            if ((unsigned)gx < WW && (unsigned)gy < HH) {
                bilinN<3>(imgb + ibase, (float)gx + fxs[it], (float)gy + fys[it], w);
                size_t ii = ibase + (size_t)gy * WW + gx;
                a0 = imga[ii];
                a1 = imga[ii + plane];
                a2 = imga[ii + 2 * plane];
            }
            lds_w[0][hy][hx] = w[0]; lds_w[1][hy][hx] = w[1]; lds_w[2][hy][hx] = w[2];
            lds_a[0][hy][hx] = a0;   lds_a[1][hy][hx] = a1;   lds_a[2][hy][hx] = a2;
        }
    }
    __syncthreads();

    // ---- Phase C: per center pixel terms ----
    float local = 0.f, lepe = 0.f;
    const float T0 = 1.f / 12.f, T1 = 2.f / 3.f;

#pragma unroll
    for (int i = 0; i < 4; ++i) {
        int p = i * 256 + tid;
        int ly = p >> 5, lx = p & 31;
        int y = ty0 + ly, x = tx0 + lx;

        size_t fi = fbase + (size_t)y * WW + x;
        float fx = flowa[fi], fy = flowa[fi + plane];
        float X = (float)x + fx, Y = (float)y + fy;

        // border mask
        float mask = sigm(X + 0.5f) * (1.f - sigm(X - ((float)WW - 0.5f)))
                   * sigm(Y + 0.5f) * (1.f - sigm(Y - ((float)HH - 0.5f)));

        // warped backward flow -> occlusion
        float wf[2];
        bilinN<2>(flowb + fbase, X, Y, wf);
        float mag = fx * fx + fy * fy + wf[0] * wf[0] + wf[1] * wf[1];
        float sx = fx + wf[0], sy = fy + wf[1];
        float d2 = sx * sx + sy * sy;
        float occ = 1.f - sigm(d2 - (0.01f * mag + 0.5f));
        mask *= occ;

        // data term
        float A = 0.f;
#pragma unroll
        for (int c = 0; c < 3; ++c) {
            float d = lds_a[c][ly + 2][lx + 2] - lds_w[c][ly + 2][lx + 2];
            A += d * d;
        }

        // smooth term (forward diffs, zero at last col/row)
        float sm = 0.f;
        if (x < WW - 1) {
            float dfx = flowa[fi + 1] - fx;
            float dfy = flowa[fi + plane + 1] - fy;
            sm += dfx * dfx + dfy * dfy;
        }
        if (y < HH - 1) {
            float dfx = flowa[fi + WW] - fx;
            float dfy = flowa[fi + plane + WW] - fy;
            sm += dfx * dfx + dfy * dfy;
        }

        // gradient term: 5-tap derivatives on imga and warped imgb
        float C = 0.f;
#pragma unroll
        for (int c = 0; c < 3; ++c) {
            float gha = T1 * (lds_a[c][ly + 2][lx + 1] - lds_a[c][ly + 2][lx + 3])
                      + T0 * (lds_a[c][ly + 2][lx + 4] - lds_a[c][ly + 2][lx]);
            float ghw = T1 * (lds_w[c][ly + 2][lx + 1] - lds_w[c][ly + 2][lx + 3])
                      + T0 * (lds_w[c][ly + 2][lx + 4] - lds_w[c][ly + 2][lx]);
            float d = gha - ghw;
            C += d * d;
            float gva = T1 * (lds_a[c][ly + 1][lx + 2] - lds_a[c][ly + 3][lx + 2])
                      + T0 * (lds_a[c][ly + 4][lx + 2] - lds_a[c][ly][lx + 2]);
            float gvw = T1 * (lds_w[c][ly + 1][lx + 2] - lds_w[c][ly + 3][lx + 2])
                      + T0 * (lds_w[c][ly + 4][lx + 2] - lds_w[c][ly][lx + 2]);
            d = gva - gvw;
            C += d * d;
        }

        local += sqrtf(A + 1e-5f) * mask             // ALPHA * data
               + sqrtf(sm + 1e-5f)                   // BETA * smooth
               + sqrtf(C + 1e-5f) * mask             // GAMMA * grad
               + 12.4f * (1.f - mask)                // MASK_COST * mask_term
               + sqrtf(d2 + 1e-5f) * mask;           // DELTA * fb contribution

        if (dir == 0) {
            float dx = fx - target[fi];
            float dy = fy - target[fi + plane];
            lepe += sqrtf(dx * dx + dy * dy);
        }
    }

    // ---- block reduction ----
#pragma unroll
    for (int off = 32; off > 0; off >>= 1) {
        local += __shfl_down(local, off);
        lepe  += __shfl_down(lepe, off);
    }
    int wid = tid >> 6;
    if ((tid & 63) == 0) { red[wid] = local; red[4 + wid] = lepe; }
    __syncthreads();
    if (tid == 0) {
        atomicAdd(&acc[0], red[0] + red[1] + red[2] + red[3]);
        if (dir == 0) atomicAdd(&acc[1], red[4] + red[5] + red[6] + red[7]);
    }
}

__global__ void finalize_kernel(const float* __restrict__ acc, float* __restrict__ out) {
    out[0] = acc[0] / (float)BB;
    out[1] = acc[1] / (float)((size_t)BB * HH * WW);
}

extern "C" void kernel_launch(void* const* d_in, const int* in_sizes, int n_in,
                              void* d_out, int out_size, void* d_ws, size_t ws_size,
                              hipStream_t stream) {
    const float* flowf  = (const float*)d_in[0];
    const float* flowb  = (const float*)d_in[1];
    const float* img1   = (const float*)d_in[2];
    const float* img2   = (const float*)d_in[3];
    const float* target = (const float*)d_in[4];
    float* out = (float*)d_out;
    float* acc = (float*)d_ws;

    hipMemsetAsync(acc, 0, 2 * sizeof(float), stream);

    dim3 grid(WW / TILE, HH / TILE, 2 * BB);
    dir_kernel<<<grid, 256, 0, stream>>>(flowf, flowb, img1, img2, target, acc);

    finalize_kernel<<<1, 1, 0, stream>>>(acc, out);
}

// Round 3
// 889.920 us; speedup vs baseline: 1.0451x; 1.0451x over previous
//
#include <hip/hip_runtime.h>

#define BB 8
#define HH 512
#define WW 1024
#define TILE 32
#define HALO 2
#define LW (TILE + 2*HALO)   // 36

__device__ __forceinline__ float sigm(float v) { return 1.0f / (1.0f + __expf(-v)); }

// load (row[x0], row[x0+1]) with x clamped to [0, W-1]
__device__ __forceinline__ float2 ld2c(const float* __restrict__ row, int x0) {
    if ((unsigned)x0 < (unsigned)(WW - 1)) {
        return *reinterpret_cast<const float2*>(row + x0);
    }
    float v = row[x0 < 0 ? 0 : WW - 1];
    return make_float2(v, v);
}

// bilinear sample of C planar channels at (gx,gy), border-clamped, float2 row taps
template<int C>
__device__ __forceinline__ void bilinN(const float* __restrict__ base,
                                       float gx, float gy, float out[C]) {
    const size_t plane = (size_t)HH * WW;
    float x0f = floorf(gx), y0f = floorf(gy);
    float ax = gx - x0f, ay = gy - y0f;
    int x0 = (int)x0f, y0 = (int)y0f;
    int y0i = min(max(y0, 0), HH - 1);
    int y1i = min(max(y0 + 1, 0), HH - 1);
    float w00 = (1.f - ay) * (1.f - ax), w01 = (1.f - ay) * ax;
    float w10 = ay * (1.f - ax), w11 = ay * ax;
#pragma unroll
    for (int c = 0; c < C; ++c) {
        const float* pl = base + c * plane;
        float2 r0 = ld2c(pl + (size_t)y0i * WW, x0);
        float2 r1 = ld2c(pl + (size_t)y1i * WW, x0);
        out[c] = w00 * r0.x + w01 * r0.y + w10 * r1.x + w11 * r1.y;
    }
}

// zero-padded read of one plane (matches jnp.pad zeros for the grad stencil)
__device__ __forceinline__ float ldz(const float* __restrict__ pl, int x, int y) {
    return ((unsigned)x < (unsigned)WW && (unsigned)y < (unsigned)HH)
         ? pl[(size_t)y * WW + x] : 0.f;
}

// Both directions in one dispatch: blockIdx.z = dir*BB + b
__global__ void dir_kernel(const float* __restrict__ flowf, const float* __restrict__ flowb_,
                           const float* __restrict__ img1, const float* __restrict__ img2,
                           const float* __restrict__ target, float* __restrict__ acc) {
    __shared__ float lds_w[3][LW][LW];  // warped imgb (0 outside image = zero-pad)
    __shared__ float red[8];

    const int z = blockIdx.z;
    const int dir = z >> 3;
    const int b = z & 7;
    const float* flowa = dir ? flowb_ : flowf;
    const float* flowb = dir ? flowf : flowb_;
    const float* imga  = dir ? img2 : img1;
    const float* imgb  = dir ? img1 : img2;

    const int tx0 = blockIdx.x * TILE;
    const int ty0 = blockIdx.y * TILE;
    const int tid = threadIdx.x;
    const size_t plane = (size_t)HH * WW;
    const size_t fbase = (size_t)(b * 2) * plane;
    const size_t ibase = (size_t)(b * 3) * plane;

    // ---- halo phase: warp imgb by flowa into LDS (serial per-slot, low reg lifetime) ----
    for (int p = tid; p < LW * LW; p += 256) {
        int hy = p / LW, hx = p - hy * LW;
        int gy = ty0 + hy - HALO, gx = tx0 + hx - HALO;
        float w[3] = {0.f, 0.f, 0.f};
        if ((unsigned)gx < (unsigned)WW && (unsigned)gy < (unsigned)HH) {
            size_t fi = fbase + (size_t)gy * WW + gx;
            float fx = flowa[fi];
            float fy = flowa[fi + plane];
            bilinN<3>(imgb + ibase, (float)gx + fx, (float)gy + fy, w);
        }
        lds_w[0][hy][hx] = w[0];
        lds_w[1][hy][hx] = w[1];
        lds_w[2][hy][hx] = w[2];
    }
    __syncthreads();

    // ---- center phase ----
    float local = 0.f, lepe = 0.f;
    const float T0 = 1.f / 12.f, T1 = 2.f / 3.f;

    for (int i = 0; i < 4; ++i) {
        int p = i * 256 + tid;
        int ly = p >> 5, lx = p & 31;
        int y = ty0 + ly, x = tx0 + lx;

        size_t fi = fbase + (size_t)y * WW + x;
        float fx = flowa[fi], fy = flowa[fi + plane];
        float X = (float)x + fx, Y = (float)y + fy;

        // border mask
        float mask = sigm(X + 0.5f) * (1.f - sigm(X - ((float)WW - 0.5f)))
                   * sigm(Y + 0.5f) * (1.f - sigm(Y - ((float)HH - 0.5f)));

        // warped backward flow -> occlusion
        float wf[2];
        bilinN<2>(flowb + fbase, X, Y, wf);
        float mag = fx * fx + fy * fy + wf[0] * wf[0] + wf[1] * wf[1];
        float sx = fx + wf[0], sy = fy + wf[1];
        float d2 = sx * sx + sy * sy;
        float occ = 1.f - sigm(d2 - (0.01f * mag + 0.5f));
        mask *= occ;

        // data term (center only -> always in-image)
        float A = 0.f;
#pragma unroll
        for (int c = 0; c < 3; ++c) {
            float av = imga[ibase + c * plane + (size_t)y * WW + x];
            float d = av - lds_w[c][ly + 2][lx + 2];
            A += d * d;
        }

        // smooth term (forward diffs, zero at last col/row)
        float sm = 0.f;
        if (x < WW - 1) {
            float dfx = flowa[fi + 1] - fx;
            float dfy = flowa[fi + plane + 1] - fy;
            sm += dfx * dfx + dfy * dfy;
        }
        if (y < HH - 1) {
            float dfx = flowa[fi + WW] - fx;
            float dfy = flowa[fi + plane + WW] - fy;
            sm += dfx * dfx + dfy * dfy;
        }

        // gradient term: 5-tap derivatives; imga from global (zero-padded), warped from LDS
        float C = 0.f;
#pragma unroll
        for (int c = 0; c < 3; ++c) {
            const float* pl = imga + ibase + c * plane;
            float gha = T1 * (ldz(pl, x - 1, y) - ldz(pl, x + 1, y))
                      + T0 * (ldz(pl, x + 2, y) - ldz(pl, x - 2, y));
            float ghw = T1 * (lds_w[c][ly + 2][lx + 1] - lds_w[c][ly + 2][lx + 3])
                      + T0 * (lds_w[c][ly + 2][lx + 4] - lds_w[c][ly + 2][lx]);
            float d = gha - ghw;
            C += d * d;
            float gva = T1 * (ldz(pl, x, y - 1) - ldz(pl, x, y + 1))
                      + T0 * (ldz(pl, x, y + 2) - ldz(pl, x, y - 2));
            float gvw = T1 * (lds_w[c][ly + 1][lx + 2] - lds_w[c][ly + 3][lx + 2])
                      + T0 * (lds_w[c][ly + 4][lx + 2] - lds_w[c][ly][lx + 2]);
            d = gva - gvw;
            C += d * d;
        }

        local += sqrtf(A + 1e-5f) * mask             // ALPHA * data
               + sqrtf(sm + 1e-5f)                   // BETA * smooth
               + sqrtf(C + 1e-5f) * mask             // GAMMA * grad
               + 12.4f * (1.f - mask)                // MASK_COST * mask_term
               + sqrtf(d2 + 1e-5f) * mask;           // DELTA * fb contribution

        if (dir == 0) {
            float dx = fx - target[fi];
            float dy = fy - target[fi + plane];
            lepe += sqrtf(dx * dx + dy * dy);
        }
    }

    // ---- block reduction ----
#pragma unroll
    for (int off = 32; off > 0; off >>= 1) {
        local += __shfl_down(local, off);
        lepe  += __shfl_down(lepe, off);
    }
    int wid = tid >> 6;
    if ((tid & 63) == 0) { red[wid] = local; red[4 + wid] = lepe; }
    __syncthreads();
    if (tid == 0) {
        atomicAdd(&acc[0], red[0] + red[1] + red[2] + red[3]);
        if (dir == 0) atomicAdd(&acc[1], red[4] + red[5] + red[6] + red[7]);
    }
}

__global__ void finalize_kernel(const float* __restrict__ acc, float* __restrict__ out) {
    out[0] = acc[0] / (float)BB;
    out[1] = acc[1] / (float)((size_t)BB * HH * WW);
}

extern "C" void kernel_launch(void* const* d_in, const int* in_sizes, int n_in,
                              void* d_out, int out_size, void* d_ws, size_t ws_size,
                              hipStream_t stream) {
    const float* flowf  = (const float*)d_in[0];
    const float* flowb  = (const float*)d_in[1];
    const float* img1   = (const float*)d_in[2];
    const float* img2   = (const float*)d_in[3];
    const float* target = (const float*)d_in[4];
    float* out = (float*)d_out;
    float* acc = (float*)d_ws;

    hipMemsetAsync(acc, 0, 2 * sizeof(float), stream);

    dim3 grid(WW / TILE, HH / TILE, 2 * BB);
    dir_kernel<<<grid, 256, 0, stream>>>(flowf, flowb, img1, img2, target, acc);

    finalize_kernel<<<1, 1, 0, stream>>>(acc, out);
}